// Round 3
// baseline (498.730 us; speedup 1.0000x reference)
//
#include <hip/hip_runtime.h>
#include <hip/hip_cooperative_groups.h>

namespace cg = cooperative_groups;

#define N_INPUTS   1024
#define MAX_HIDDEN 2048
#define MAX_LAYERS 4
#define TOTAL_HIDDEN (MAX_HIDDEN * MAX_LAYERS)      // 8192
#define N_OUTPUTS  512
#define MAX_CONN   2048
#define MAX_OUT_CONN 4096
#define N_VALUES   (N_INPUTS + TOTAL_HIDDEN)        // 9216

// 8-connection packet: 2x int4 ids, 2x float4 weights, 2x int4 mask, gather from LDS.
__device__ __forceinline__ float dot8(const int* __restrict__ idp,
                                      const float* __restrict__ wp,
                                      const int* __restrict__ mp,
                                      const float* __restrict__ vals)
{
    int4   ia = *reinterpret_cast<const int4*>(idp);
    int4   ib = *reinterpret_cast<const int4*>(idp + 4);
    float4 wa = *reinterpret_cast<const float4*>(wp);
    float4 wb = *reinterpret_cast<const float4*>(wp + 4);
    int4   ma = *reinterpret_cast<const int4*>(mp);
    int4   mb = *reinterpret_cast<const int4*>(mp + 4);

    float v0 = ma.x ? vals[ia.x] : 0.f;
    float v1 = ma.y ? vals[ia.y] : 0.f;
    float v2 = ma.z ? vals[ia.z] : 0.f;
    float v3 = ma.w ? vals[ia.w] : 0.f;
    float v4 = mb.x ? vals[ib.x] : 0.f;
    float v5 = mb.y ? vals[ib.y] : 0.f;
    float v6 = mb.z ? vals[ib.z] : 0.f;
    float v7 = mb.w ? vals[ib.w] : 0.f;

    float s = 0.f;
    s = fmaf(v0, wa.x, s);
    s = fmaf(v1, wa.y, s);
    s = fmaf(v2, wa.z, s);
    s = fmaf(v3, wa.w, s);
    s = fmaf(v4, wb.x, s);
    s = fmaf(v5, wb.y, s);
    s = fmaf(v6, wb.z, s);
    s = fmaf(v7, wb.w, s);
    return s;
}

__global__ void __launch_bounds__(512, 2)
fused_net(const float* __restrict__ g_in,
          const int* __restrict__ h_ids, const float* __restrict__ h_w,
          const int* __restrict__ h_cm,  const int* __restrict__ h_am,
          const int* __restrict__ o_ids, const float* __restrict__ o_w,
          const int* __restrict__ o_cm,
          float* __restrict__ out, float* __restrict__ gvals)
{
    __shared__ float vals[N_VALUES];
    __shared__ float psum[8];

    const int tid  = threadIdx.x;
    const int wave = tid >> 6;
    const int lane = tid & 63;

    // ---- init LDS: inputs in [0,1024), zeros elsewhere ----
    {
        const float4* g4 = reinterpret_cast<const float4*>(g_in);
        float4* s4 = reinterpret_cast<float4*>(vals);
        for (int i = tid; i < (N_VALUES >> 2); i += 512) {
            float4 v;
            if (i < (N_INPUTS >> 2)) v = g4[i];
            else { v.x = 0.f; v.y = 0.f; v.z = 0.f; v.w = 0.f; }
            s4[i] = v;
        }
    }
    __syncthreads();

    cg::grid_group grid = cg::this_grid();

    // ---- hidden layers: 2048 neurons, 1 per wave, 256 blocks x 8 waves ----
    for (int k = 0; k < MAX_LAYERS; ++k) {
        const int start  = k * MAX_HIDDEN;
        const int neuron = (blockIdx.x << 3) + wave;
        const size_t row = (size_t)(start + neuron) * MAX_CONN;
        const int*   idrow = h_ids + row;
        const float* wrow  = h_w   + row;
        const int*   mrow  = h_cm  + row;

        float sum = 0.f;
        #pragma unroll
        for (int j = 0; j < MAX_CONN / 512; ++j) {
            const int c = (lane << 3) + (j << 9);
            sum += dot8(idrow + c, wrow + c, mrow + c, vals);
        }

        #pragma unroll
        for (int off = 32; off > 0; off >>= 1)
            sum += __shfl_xor(sum, off, 64);

        if (lane == 0) {
            float a = tanhf(sum);
            if (h_am[start + neuron] == 0) a = 0.f;
            gvals[N_INPUTS + start + neuron] = a;
        }
        __threadfence();          // release: make activations visible device-wide
        grid.sync();
        __threadfence();          // acquire: invalidate stale cached lines

        // refresh LDS with this layer's 2048 activations
        {
            const float4* g4 = reinterpret_cast<const float4*>(gvals + N_INPUTS + start);
            float4* s4 = reinterpret_cast<float4*>(vals + N_INPUTS + start);
            for (int i = tid; i < (MAX_HIDDEN >> 2); i += 512) s4[i] = g4[i];
        }
        __syncthreads();
    }

    // ---- output layer: 512 neurons, 2 per block, 4 waves per neuron ----
    {
        const int wq = wave & 3;               // quarter within neuron
        const int on = (blockIdx.x << 1) + (wave >> 2);
        const size_t row = (size_t)on * MAX_OUT_CONN + (size_t)(wq << 10);
        const int*   idrow = o_ids + row;
        const float* wrow  = o_w   + row;
        const int*   mrow  = o_cm  + row;

        float sum = 0.f;
        #pragma unroll
        for (int j = 0; j < 1024 / 512; ++j) {
            const int c = (lane << 3) + (j << 9);
            sum += dot8(idrow + c, wrow + c, mrow + c, vals);
        }

        #pragma unroll
        for (int off = 32; off > 0; off >>= 1)
            sum += __shfl_xor(sum, off, 64);

        if (lane == 0) psum[wave] = sum;
        __syncthreads();

        if (tid < 2) {
            float t = psum[(tid << 2) + 0] + psum[(tid << 2) + 1]
                    + psum[(tid << 2) + 2] + psum[(tid << 2) + 3];
            out[(blockIdx.x << 1) + tid] = t;
        }
    }
}

extern "C" void kernel_launch(void* const* d_in, const int* in_sizes, int n_in,
                              void* d_out, int out_size, void* d_ws, size_t ws_size,
                              hipStream_t stream) {
    const float* input_values = (const float*)d_in[0];
    const int*   h_ids        = (const int*)d_in[1];
    const float* h_w          = (const float*)d_in[2];
    const int*   h_cm         = (const int*)d_in[3];
    const int*   h_am         = (const int*)d_in[4];
    const int*   o_ids        = (const int*)d_in[5];
    const float* o_w          = (const float*)d_in[6];
    const int*   o_cm         = (const int*)d_in[7];
    float* out  = (float*)d_out;
    float* vals = (float*)d_ws;   // activations staging: 9216 floats

    void* args[] = { (void*)&input_values, (void*)&h_ids, (void*)&h_w, (void*)&h_cm,
                     (void*)&h_am, (void*)&o_ids, (void*)&o_w, (void*)&o_cm,
                     (void*)&out, (void*)&vals };

    hipLaunchCooperativeKernel((const void*)fused_net, dim3(256), dim3(512),
                               args, 0, stream);
}

// Round 4
// 58.646 us; speedup vs baseline: 8.5040x; 8.5040x over previous
//
#include <hip/hip_runtime.h>

#define N_INPUTS   1024
#define MAX_HIDDEN 2048
#define MAX_LAYERS 4
#define TOTAL_HIDDEN (MAX_HIDDEN * MAX_LAYERS)      // 8192
#define N_OUTPUTS  512
#define MAX_CONN   2048
#define MAX_OUT_CONN 4096
#define N_VALUES   (N_INPUTS + TOTAL_HIDDEN)        // 9216

// Stage values prefix into LDS: [0,1024) from inputs, [1024, 1024+staged_hidden)
// from gvals (hidden activations), zeros beyond (future layers must read 0).
__device__ __forceinline__ void stage_values(float* __restrict__ vals,
                                             const float* __restrict__ g_in,
                                             const float* __restrict__ gvals,
                                             int staged_hidden)
{
    const float4* in4 = reinterpret_cast<const float4*>(g_in);
    const float4* gv4 = reinterpret_cast<const float4*>(gvals);
    float4* s4 = reinterpret_cast<float4*>(vals);
    const int nin4 = N_INPUTS >> 2;                       // 256
    const int pre4 = (N_INPUTS + staged_hidden) >> 2;     // prefix end
    for (int i = threadIdx.x; i < (N_VALUES >> 2); i += blockDim.x) {
        float4 v;
        if (i < nin4)      v = in4[i];
        else if (i < pre4) v = gv4[i - nin4];
        else { v.x = 0.f; v.y = 0.f; v.z = 0.f; v.w = 0.f; }
        s4[i] = v;
    }
}

// Hidden layer: 2048 neurons x 2048 conns. 256 blocks x 1024 threads.
// 2 waves per neuron (1024 conns each); per lane: 2 packets of 8 conns,
// explicitly prefetched into registers before the LDS gathers.
__global__ void __launch_bounds__(1024, 4)
hidden_layer_kernel(const float* __restrict__ g_in,
                    float* __restrict__ gvals,            // hidden activations [8192]
                    const int* __restrict__ ids,
                    const float* __restrict__ wts,
                    const int* __restrict__ cmask,
                    const int* __restrict__ amask,
                    int row_base,                          // layer start in hidden space
                    int staged_hidden)                     // = row_base
{
    __shared__ float vals[N_VALUES];
    __shared__ float psum[16];

    stage_values(vals, g_in, gvals, staged_hidden);
    __syncthreads();

    const int tid  = threadIdx.x;
    const int wave = tid >> 6;
    const int lane = tid & 63;

    const int neuron = (blockIdx.x << 3) + (wave >> 1);    // 8 neurons/block
    const size_t row = (size_t)(row_base + neuron) * MAX_CONN + ((size_t)(wave & 1) << 10);

    // ---- prefetch 2 packets (12 x 16B loads) ----
    int4 IA[2], IB[2], MA[2], MB[2];
    float4 WA[2], WB[2];
    #pragma unroll
    for (int j = 0; j < 2; ++j) {
        const size_t c = row + (lane << 3) + (j << 9);
        IA[j] = *reinterpret_cast<const int4*>(ids + c);
        IB[j] = *reinterpret_cast<const int4*>(ids + c + 4);
        WA[j] = *reinterpret_cast<const float4*>(wts + c);
        WB[j] = *reinterpret_cast<const float4*>(wts + c + 4);
        MA[j] = *reinterpret_cast<const int4*>(cmask + c);
        MB[j] = *reinterpret_cast<const int4*>(cmask + c + 4);
    }

    float sum = 0.f;
    #pragma unroll
    for (int j = 0; j < 2; ++j) {
        float v0 = MA[j].x ? vals[IA[j].x] : 0.f;
        float v1 = MA[j].y ? vals[IA[j].y] : 0.f;
        float v2 = MA[j].z ? vals[IA[j].z] : 0.f;
        float v3 = MA[j].w ? vals[IA[j].w] : 0.f;
        float v4 = MB[j].x ? vals[IB[j].x] : 0.f;
        float v5 = MB[j].y ? vals[IB[j].y] : 0.f;
        float v6 = MB[j].z ? vals[IB[j].z] : 0.f;
        float v7 = MB[j].w ? vals[IB[j].w] : 0.f;
        sum = fmaf(v0, WA[j].x, sum);
        sum = fmaf(v1, WA[j].y, sum);
        sum = fmaf(v2, WA[j].z, sum);
        sum = fmaf(v3, WA[j].w, sum);
        sum = fmaf(v4, WB[j].x, sum);
        sum = fmaf(v5, WB[j].y, sum);
        sum = fmaf(v6, WB[j].z, sum);
        sum = fmaf(v7, WB[j].w, sum);
    }

    #pragma unroll
    for (int off = 32; off > 0; off >>= 1)
        sum += __shfl_xor(sum, off, 64);

    if (lane == 0) psum[wave] = sum;
    __syncthreads();

    if (tid < 8) {
        const int n = (blockIdx.x << 3) + tid;
        float s = psum[tid << 1] + psum[(tid << 1) + 1];
        float a = tanhf(s);
        if (amask[row_base + n] == 0) a = 0.f;
        gvals[row_base + n] = a;
    }
}

// Output layer: 512 neurons x 4096 conns. 256 blocks x 1024 threads.
// 2 neurons/block, 8 waves per neuron, 1 packet (8 conns) per lane.
__global__ void __launch_bounds__(1024, 4)
output_layer_kernel(const float* __restrict__ g_in,
                    const float* __restrict__ gvals,
                    const int* __restrict__ ids,
                    const float* __restrict__ wts,
                    const int* __restrict__ cmask,
                    float* __restrict__ out)
{
    __shared__ float vals[N_VALUES];
    __shared__ float psum[16];

    stage_values(vals, g_in, gvals, TOTAL_HIDDEN);
    __syncthreads();

    const int tid  = threadIdx.x;
    const int wave = tid >> 6;
    const int lane = tid & 63;

    const int neuron = (blockIdx.x << 1) + (wave >> 3);
    const size_t row = (size_t)neuron * MAX_OUT_CONN + ((size_t)(wave & 7) << 9);
    const size_t c = row + (lane << 3);

    int4 ia = *reinterpret_cast<const int4*>(ids + c);
    int4 ib = *reinterpret_cast<const int4*>(ids + c + 4);
    float4 wa = *reinterpret_cast<const float4*>(wts + c);
    float4 wb = *reinterpret_cast<const float4*>(wts + c + 4);
    int4 ma = *reinterpret_cast<const int4*>(cmask + c);
    int4 mb = *reinterpret_cast<const int4*>(cmask + c + 4);

    float v0 = ma.x ? vals[ia.x] : 0.f;
    float v1 = ma.y ? vals[ia.y] : 0.f;
    float v2 = ma.z ? vals[ia.z] : 0.f;
    float v3 = ma.w ? vals[ia.w] : 0.f;
    float v4 = mb.x ? vals[ib.x] : 0.f;
    float v5 = mb.y ? vals[ib.y] : 0.f;
    float v6 = mb.z ? vals[ib.z] : 0.f;
    float v7 = mb.w ? vals[ib.w] : 0.f;

    float sum = 0.f;
    sum = fmaf(v0, wa.x, sum);
    sum = fmaf(v1, wa.y, sum);
    sum = fmaf(v2, wa.z, sum);
    sum = fmaf(v3, wa.w, sum);
    sum = fmaf(v4, wb.x, sum);
    sum = fmaf(v5, wb.y, sum);
    sum = fmaf(v6, wb.z, sum);
    sum = fmaf(v7, wb.w, sum);

    #pragma unroll
    for (int off = 32; off > 0; off >>= 1)
        sum += __shfl_xor(sum, off, 64);

    if (lane == 0) psum[wave] = sum;
    __syncthreads();

    if (tid < 2) {
        float s = 0.f;
        #pragma unroll
        for (int q = 0; q < 8; ++q) s += psum[(tid << 3) + q];
        out[(blockIdx.x << 1) + tid] = s;
    }
}

extern "C" void kernel_launch(void* const* d_in, const int* in_sizes, int n_in,
                              void* d_out, int out_size, void* d_ws, size_t ws_size,
                              hipStream_t stream) {
    const float* input_values = (const float*)d_in[0];
    const int*   h_ids        = (const int*)d_in[1];
    const float* h_w          = (const float*)d_in[2];
    const int*   h_cm         = (const int*)d_in[3];
    const int*   h_am         = (const int*)d_in[4];
    const int*   o_ids        = (const int*)d_in[5];
    const float* o_w          = (const float*)d_in[6];
    const int*   o_cm         = (const int*)d_in[7];
    float* out   = (float*)d_out;
    float* gvals = (float*)d_ws;   // hidden activations: 8192 floats

    for (int k = 0; k < MAX_LAYERS; ++k) {
        const int start = k * MAX_HIDDEN;
        hidden_layer_kernel<<<256, 1024, 0, stream>>>(
            input_values, gvals, h_ids, h_w, h_cm, h_am, start, start);
    }

    output_layer_kernel<<<256, 1024, 0, stream>>>(
        input_values, gvals, o_ids, o_w, o_cm, out);
}